// Round 6
// baseline (95.152 us; speedup 1.0000x reference)
//
#include <hip/hip_runtime.h>
#include <hip/hip_bf16.h>

#define NSEN 4000
#define NP   4096
#define DIN  128
#define DOUT 128
#define EDIM 16
#define BATCH 8

typedef __attribute__((ext_vector_type(8))) short bf16x8;
typedef __attribute__((ext_vector_type(4))) float f32x4;

__device__ __forceinline__ unsigned short f2bf(float f) {
  unsigned int u = __float_as_uint(f);
  unsigned int r = (u + 0x7FFFu + ((u >> 16) & 1u)) >> 16;
  return (unsigned short)r;
}
__device__ __forceinline__ float bf2f(unsigned short s) {
  unsigned int u = ((unsigned int)s) << 16;
  return __uint_as_float(u);
}

__device__ __forceinline__ void gl_lds16(const void* g, void* l) {
  __builtin_amdgcn_global_load_lds((const __attribute__((address_space(1))) void*)g,
                                   (__attribute__((address_space(3))) void*)l, 16, 0, 0);
}

// ---------------- Kernel 1: P = exp(relu(E1 @ E2^T)) unnorm -> bf16; rinv = 1/rowsum
// MFMA hi/lo split. 512 threads, 8 waves. Block 250 transposes W.
__global__ __launch_bounds__(512) void k_adj(const float* __restrict__ E1,
                                             const float* __restrict__ E2,
                                             const float* __restrict__ W,
                                             unsigned short* __restrict__ adjp,
                                             float* __restrict__ rinv,
                                             unsigned short* __restrict__ Wt) {
  __shared__ float rsum[8][16];
  if (blockIdx.x == NSEN / 16) {
    for (int i = threadIdx.x; i < DIN * DOUT; i += 512) {
      int o = i >> 7, f = i & 127;
      Wt[i] = f2bf(W[(size_t)f * DOUT + o]);
    }
    return;
  }
  const int tid = threadIdx.x;
  const int lane = tid & 63, wv = tid >> 6;
  const int lr = lane & 15, lq = lane >> 4;
  const int n0 = blockIdx.x * 16;

  float a[8];
  {
    const float* e1p = &E1[(size_t)(n0 + lr) * EDIM + (lq & 1) * 8];
    *(float4*)&a[0] = *(const float4*)e1p;
    *(float4*)&a[4] = *(const float4*)(e1p + 4);
  }
  bf16x8 af1, af2;
#pragma unroll
  for (int j = 0; j < 8; j++) {
    unsigned short hs = f2bf(a[j]);
    af1[j] = (short)hs;
    float lo = a[j] - bf2f(hs);
    af2[j] = (lq < 2) ? (short)f2bf(lo) : (short)0;
  }

  float rs[4] = {0.f, 0.f, 0.f, 0.f};
  for (int t = wv; t < NSEN / 16; t += 8) {
    const int m = t * 16 + lr;
    float bv[8];
    const float* e2p = &E2[(size_t)m * EDIM + (lq & 1) * 8];
    *(float4*)&bv[0] = *(const float4*)e2p;
    *(float4*)&bv[4] = *(const float4*)(e2p + 4);
    bf16x8 bfrag;
#pragma unroll
    for (int j = 0; j < 8; j++) {
      unsigned short hs = f2bf(bv[j]);
      if (lq < 2) bfrag[j] = (short)hs;
      else        bfrag[j] = (short)f2bf(bv[j] - bf2f(hs));
    }
    f32x4 c = (f32x4){0.f, 0.f, 0.f, 0.f};
    c = __builtin_amdgcn_mfma_f32_16x16x32_bf16(af1, bfrag, c, 0, 0, 0);
    c = __builtin_amdgcn_mfma_f32_16x16x32_bf16(af2, bfrag, c, 0, 0, 0);
#pragma unroll
    for (int i = 0; i < 4; i++) {
      float p = __expf(fmaxf(c[i], 0.f));
      rs[i] += p;
      adjp[(size_t)(n0 + lq * 4 + i) * NP + t * 16 + lr] = f2bf(p);
    }
  }
  for (int i = tid; i < 16 * (NP - NSEN); i += 512) {
    int r = i / (NP - NSEN), c = i % (NP - NSEN);
    adjp[(size_t)(n0 + r) * NP + NSEN + c] = 0;
  }
#pragma unroll
  for (int i = 0; i < 4; i++) {
    rs[i] += __shfl_xor(rs[i], 1, 64);
    rs[i] += __shfl_xor(rs[i], 2, 64);
    rs[i] += __shfl_xor(rs[i], 4, 64);
    rs[i] += __shfl_xor(rs[i], 8, 64);
  }
  if (lr == 0) {
#pragma unroll
    for (int i = 0; i < 4; i++) rsum[wv][lq * 4 + i] = rs[i];
  }
  __syncthreads();
  if (tid < 16) {
    float s = 0.f;
#pragma unroll
    for (int w = 0; w < 8; w++) s += rsum[w][tid];
    rinv[n0 + tid] = 1.0f / s;
  }
}

// ---------------- Kernel 2: xpt[b*128+f][m] = bf16(x[b][m][f]), cols m>=NSEN -> 0
__global__ __launch_bounds__(256) void k_xpt(const float* __restrict__ x,
                                             unsigned short* __restrict__ xpt) {
  __shared__ unsigned short tile[64][72];
  const int t = threadIdx.x;
  const int m0 = blockIdx.x * 64;
  const int f0 = blockIdx.y * 64;
  const int b  = blockIdx.z;
  const int f4 = t & 15, mrow = t >> 4;
#pragma unroll
  for (int rep = 0; rep < 4; rep++) {
    int ml = mrow + rep * 16;
    int m = m0 + ml;
    float4 v = make_float4(0.f, 0.f, 0.f, 0.f);
    if (m < NSEN) v = *(const float4*)&x[((size_t)b * NSEN + m) * DIN + f0 + f4 * 4];
    tile[f4*4+0][ml] = f2bf(v.x);
    tile[f4*4+1][ml] = f2bf(v.y);
    tile[f4*4+2][ml] = f2bf(v.z);
    tile[f4*4+3][ml] = f2bf(v.w);
  }
  __syncthreads();
  const int seg = t & 7, fl0 = t >> 3;
#pragma unroll
  for (int it = 0; it < 2; it++) {
    int fl = fl0 + it * 32;
    int j = b * DIN + f0 + fl;
    uint4 v = *(const uint4*)&tile[fl][seg * 8];
    *(uint4*)&xpt[(size_t)j * NP + m0 + seg * 8] = v;
  }
}

// ---------------- Kernel 3: split-K partial GEMM: part[kh] = A[:,khalf] @ Bt^T ---
// BM=64, BN=128, BK=64, split-K=2. grid 63x8x2 = 1008 blocks -> 3 blocks/CU
// (48 KB LDS 2-buffer). Counted vmcnt(6) depth-1 prefetch, split lgkmcnt,
// setprio, XOR-swizzled LDS via pre-swizzled source.
__global__ __launch_bounds__(256, 3) void k_gemm1(const unsigned short* __restrict__ A,
                                                  const unsigned short* __restrict__ Bt,
                                                  unsigned short* __restrict__ part) {
  __shared__ __align__(16) unsigned short smem[24576];  // 48 KB: A 2x4096 | B 2x8192
  const int tid = threadIdx.x;
  const int lane = tid & 63, wv = tid >> 6;
  const int wr = wv >> 1, wc = wv & 1;     // 2 x 2 wave grid, wave tile 32x64
  const int lr = lane & 15, lq = lane >> 4;
  const int m0 = blockIdx.x * 64;   // x%8 -> XCD cohort shares A panel in L2
  const int b  = blockIdx.y;
  const int kh = blockIdx.z;
  const int c0 = b * 128;
  const int kb0 = kh * 2048;
  unsigned short* tA0 = smem;           // 2 * 4096
  unsigned short* tB0 = smem + 8192;    // 2 * 8192

  f32x4 acc[2][4];
#pragma unroll
  for (int p = 0; p < 2; p++)
#pragma unroll
    for (int q = 0; q < 4; q++) acc[p][q] = (f32x4){0.f, 0.f, 0.f, 0.f};

  // 6 gl_lds16 per thread per STAGE (2 A + 4 B); source k-chunk pre-swizzled
#define STAGE(bufi, kb)                                                              \
  {                                                                                  \
    _Pragma("unroll")                                                                \
    for (int s = 0; s < 2; s++) {                                                    \
      int idx = s * 256 + tid;                                                       \
      int row = idx >> 3;                                                            \
      int kc = ((idx & 7) ^ (row & 7)) << 3;                                         \
      gl_lds16(&A[(size_t)(m0 + row) * NP + (kb) + kc], &tA0[(bufi)*4096 + idx*8]);  \
    }                                                                                \
    _Pragma("unroll")                                                                \
    for (int s = 0; s < 4; s++) {                                                    \
      int idx = s * 256 + tid;                                                       \
      int row = idx >> 3;                                                            \
      int kc = ((idx & 7) ^ (row & 7)) << 3;                                         \
      gl_lds16(&Bt[(size_t)(c0 + row) * NP + (kb) + kc], &tB0[(bufi)*8192 + idx*8]); \
    }                                                                                \
  }

  STAGE(0, kb0);

  for (int it = 0; it < 32; ++it) {
    const int cur = it & 1;
    if (it < 31) {
      STAGE(cur ^ 1, kb0 + (it + 1) * 64);
      asm volatile("s_waitcnt vmcnt(6)" ::: "memory");  // cur's 6 landed; next 6 in flight
    } else {
      asm volatile("s_waitcnt vmcnt(0)" ::: "memory");
    }
    __builtin_amdgcn_s_barrier();

    bf16x8 af0[2], bf0[4], af1[2], bf1[4];
    {
      const int koff0 = (lq * 8) ^ ((lr & 7) << 3);
#pragma unroll
      for (int p = 0; p < 2; p++)
        af0[p] = *(const bf16x8*)&tA0[cur * 4096 + (wr * 32 + p * 16 + lr) * 64 + koff0];
#pragma unroll
      for (int q = 0; q < 4; q++)
        bf0[q] = *(const bf16x8*)&tB0[cur * 8192 + (wc * 64 + q * 16 + lr) * 64 + koff0];
    }
    __builtin_amdgcn_sched_barrier(0);  // keep sk0 reads first in issue order
    {
      const int koff1 = (32 + lq * 8) ^ ((lr & 7) << 3);
#pragma unroll
      for (int p = 0; p < 2; p++)
        af1[p] = *(const bf16x8*)&tA0[cur * 4096 + (wr * 32 + p * 16 + lr) * 64 + koff1];
#pragma unroll
      for (int q = 0; q < 4; q++)
        bf1[q] = *(const bf16x8*)&tB0[cur * 8192 + (wc * 64 + q * 16 + lr) * 64 + koff1];
    }
    asm volatile("s_waitcnt lgkmcnt(6)" ::: "memory");  // sk0's 6 reads done
    __builtin_amdgcn_sched_barrier(0);
    __builtin_amdgcn_s_setprio(1);
#pragma unroll
    for (int p = 0; p < 2; p++)
#pragma unroll
      for (int q = 0; q < 4; q++)
        acc[p][q] = __builtin_amdgcn_mfma_f32_16x16x32_bf16(af0[p], bf0[q], acc[p][q], 0, 0, 0);
    asm volatile("s_waitcnt lgkmcnt(0)" ::: "memory");
    __builtin_amdgcn_sched_barrier(0);
#pragma unroll
    for (int p = 0; p < 2; p++)
#pragma unroll
      for (int q = 0; q < 4; q++)
        acc[p][q] = __builtin_amdgcn_mfma_f32_16x16x32_bf16(af1[p], bf1[q], acc[p][q], 0, 0, 0);
    __builtin_amdgcn_s_setprio(0);
    __builtin_amdgcn_s_barrier();
  }
#undef STAGE

  // epilogue: bf16 partial store part[kh][b][m][f]
  unsigned short* pdst = part + ((size_t)(kh * BATCH + b) * NP + m0) * DIN;
#pragma unroll
  for (int p = 0; p < 2; p++)
#pragma unroll
    for (int q = 0; q < 4; q++) {
      const int col = wc * 64 + q * 16 + lr;
#pragma unroll
      for (int i = 0; i < 4; i++) {
        const int row = wr * 32 + p * 16 + lq * 4 + i;
        pdst[row * DIN + col] = f2bf(acc[p][q][i]);
      }
    }
}

// ---------------- Kernel 4: out = relu(((p0+p1) * rinv) @ W + bias) --------------
__global__ __launch_bounds__(256, 2) void k_fin(const unsigned short* __restrict__ part,
                                                const unsigned short* __restrict__ Wt,
                                                const float* __restrict__ rinv,
                                                const float* __restrict__ bias,
                                                float* __restrict__ out) {
  __shared__ __align__(16) unsigned short eps[64 * 136];
  const int tid = threadIdx.x;
  const int lane = tid & 63, wv = tid >> 6;
  const int wr = wv >> 1, wc = wv & 1;
  const int lr = lane & 15, lq = lane >> 4;
  const int m0 = blockIdx.x * 64;
  const int b = blockIdx.y;
  const size_t base = ((size_t)b * NP + m0) * DIN;
  const size_t khoff = (size_t)BATCH * NP * DIN;

  bf16x8 wf[4][4];  // [q][ks]
#pragma unroll
  for (int q = 0; q < 4; q++)
#pragma unroll
    for (int ks = 0; ks < 4; ks++)
      wf[q][ks] = *(const bf16x8*)&Wt[(size_t)(wc * 64 + q * 16 + lr) * DIN + ks * 32 + lq * 8];

  // combine partials: 64 rows x 16 8-col chunks = 1024 chunks, 4 per thread
#pragma unroll
  for (int s = 0; s < 4; s++) {
    int c = s * 256 + tid;
    int row = c >> 4, col = (c & 15) * 8;
    bf16x8 p0 = *(const bf16x8*)&part[base + row * DIN + col];
    bf16x8 p1 = *(const bf16x8*)&part[khoff + base + row * DIN + col];
    float rv = rinv[m0 + row];
    unsigned short tmp[8];
#pragma unroll
    for (int j = 0; j < 8; j++)
      tmp[j] = f2bf((bf2f((unsigned short)p0[j]) + bf2f((unsigned short)p1[j])) * rv);
    *(bf16x8*)&eps[row * 136 + col] = *(bf16x8*)tmp;
  }
  __syncthreads();

  f32x4 acc2[2][4];
#pragma unroll
  for (int p = 0; p < 2; p++)
#pragma unroll
    for (int q = 0; q < 4; q++) acc2[p][q] = (f32x4){0.f, 0.f, 0.f, 0.f};

#pragma unroll
  for (int ks = 0; ks < 4; ks++) {
    bf16x8 a2[2];
#pragma unroll
    for (int p = 0; p < 2; p++)
      a2[p] = *(const bf16x8*)&eps[(wr * 32 + p * 16 + lr) * 136 + ks * 32 + lq * 8];
#pragma unroll
    for (int p = 0; p < 2; p++)
#pragma unroll
      for (int q = 0; q < 4; q++)
        acc2[p][q] = __builtin_amdgcn_mfma_f32_16x16x32_bf16(a2[p], wf[q][ks], acc2[p][q], 0, 0, 0);
  }

#pragma unroll
  for (int p = 0; p < 2; p++)
#pragma unroll
    for (int q = 0; q < 4; q++) {
      const int o = wc * 64 + q * 16 + lr;
      const float bb = bias[o];
#pragma unroll
      for (int i = 0; i < 4; i++) {
        const int n = m0 + wr * 32 + p * 16 + lq * 4 + i;
        if (n < NSEN)
          out[((size_t)b * NSEN + n) * DOUT + o] = fmaxf(acc2[p][q][i] + bb, 0.f);
      }
    }
}

// ---------------- launch ---------------------------------------------------------
extern "C" void kernel_launch(void* const* d_in, const int* in_sizes, int n_in,
                              void* d_out, int out_size, void* d_ws, size_t ws_size,
                              hipStream_t stream) {
  const float* x    = (const float*)d_in[0];
  const float* E1   = (const float*)d_in[1];
  const float* E2   = (const float*)d_in[2];
  const float* W    = (const float*)d_in[3];
  const float* bias = (const float*)d_in[4];
  float* out = (float*)d_out;

  char* ws = (char*)d_ws;
  // layout: adjp 33554432 | xpt 8388608 | Wt 32768 | rinv 16384 | part 16777216 (~56 MiB)
  unsigned short* adjp = (unsigned short*)(ws);
  unsigned short* xpt  = (unsigned short*)(ws + 33554432);
  unsigned short* wt   = (unsigned short*)(ws + 33554432 + 8388608);
  float*          rinv = (float*)(ws + 33554432 + 8388608 + 32768);
  unsigned short* part = (unsigned short*)(ws + 33554432 + 8388608 + 32768 + 16384);

  k_adj<<<dim3(NSEN / 16 + 1), dim3(512), 0, stream>>>(E1, E2, W, adjp, rinv, wt);
  k_xpt<<<dim3(NP / 64, DIN / 64, BATCH), dim3(256), 0, stream>>>(x, xpt);
  k_gemm1<<<dim3(63, BATCH, 2), dim3(256), 0, stream>>>(adjp, xpt, part);
  k_fin<<<dim3(63, BATCH), dim3(256), 0, stream>>>(part, wt, rinv, bias, out);
}

// Round 7
// 80.607 us; speedup vs baseline: 1.1804x; 1.1804x over previous
//
#include <hip/hip_runtime.h>
#include <hip/hip_bf16.h>

#define NSEN 4000
#define NP   4096
#define DIN  128
#define DOUT 128
#define EDIM 16
#define BATCH 8

typedef __attribute__((ext_vector_type(8))) short bf16x8;
typedef __attribute__((ext_vector_type(4))) float f32x4;

__device__ __forceinline__ unsigned short f2bf(float f) {
  unsigned int u = __float_as_uint(f);
  unsigned int r = (u + 0x7FFFu + ((u >> 16) & 1u)) >> 16;
  return (unsigned short)r;
}
__device__ __forceinline__ float bf2f(unsigned short s) {
  unsigned int u = ((unsigned int)s) << 16;
  return __uint_as_float(u);
}

__device__ __forceinline__ void gl_lds16(const void* g, void* l) {
  __builtin_amdgcn_global_load_lds((const __attribute__((address_space(1))) void*)g,
                                   (__attribute__((address_space(3))) void*)l, 16, 0, 0);
}

// ---------------- Kernel 1: P = exp(relu(E1 @ E2^T)) unnorm -> bf16; rinv = 1/rowsum
// MFMA hi/lo split. 512 threads, 8 waves. Block 250 transposes W.
__global__ __launch_bounds__(512) void k_adj(const float* __restrict__ E1,
                                             const float* __restrict__ E2,
                                             const float* __restrict__ W,
                                             unsigned short* __restrict__ adjp,
                                             float* __restrict__ rinv,
                                             unsigned short* __restrict__ Wt) {
  __shared__ float rsum[8][16];
  if (blockIdx.x == NSEN / 16) {
    for (int i = threadIdx.x; i < DIN * DOUT; i += 512) {
      int o = i >> 7, f = i & 127;
      Wt[i] = f2bf(W[(size_t)f * DOUT + o]);
    }
    return;
  }
  const int tid = threadIdx.x;
  const int lane = tid & 63, wv = tid >> 6;
  const int lr = lane & 15, lq = lane >> 4;
  const int n0 = blockIdx.x * 16;

  float a[8];
  {
    const float* e1p = &E1[(size_t)(n0 + lr) * EDIM + (lq & 1) * 8];
    *(float4*)&a[0] = *(const float4*)e1p;
    *(float4*)&a[4] = *(const float4*)(e1p + 4);
  }
  bf16x8 af1, af2;
#pragma unroll
  for (int j = 0; j < 8; j++) {
    unsigned short hs = f2bf(a[j]);
    af1[j] = (short)hs;
    float lo = a[j] - bf2f(hs);
    af2[j] = (lq < 2) ? (short)f2bf(lo) : (short)0;
  }

  float rs[4] = {0.f, 0.f, 0.f, 0.f};
  for (int t = wv; t < NSEN / 16; t += 8) {
    const int m = t * 16 + lr;
    float bv[8];
    const float* e2p = &E2[(size_t)m * EDIM + (lq & 1) * 8];
    *(float4*)&bv[0] = *(const float4*)e2p;
    *(float4*)&bv[4] = *(const float4*)(e2p + 4);
    bf16x8 bfrag;
#pragma unroll
    for (int j = 0; j < 8; j++) {
      unsigned short hs = f2bf(bv[j]);
      if (lq < 2) bfrag[j] = (short)hs;
      else        bfrag[j] = (short)f2bf(bv[j] - bf2f(hs));
    }
    f32x4 c = (f32x4){0.f, 0.f, 0.f, 0.f};
    c = __builtin_amdgcn_mfma_f32_16x16x32_bf16(af1, bfrag, c, 0, 0, 0);
    c = __builtin_amdgcn_mfma_f32_16x16x32_bf16(af2, bfrag, c, 0, 0, 0);
#pragma unroll
    for (int i = 0; i < 4; i++) {
      float p = __expf(fmaxf(c[i], 0.f));
      rs[i] += p;
      adjp[(size_t)(n0 + lq * 4 + i) * NP + t * 16 + lr] = f2bf(p);
    }
  }
  for (int i = tid; i < 16 * (NP - NSEN); i += 512) {
    int r = i / (NP - NSEN), c = i % (NP - NSEN);
    adjp[(size_t)(n0 + r) * NP + NSEN + c] = 0;
  }
#pragma unroll
  for (int i = 0; i < 4; i++) {
    rs[i] += __shfl_xor(rs[i], 1, 64);
    rs[i] += __shfl_xor(rs[i], 2, 64);
    rs[i] += __shfl_xor(rs[i], 4, 64);
    rs[i] += __shfl_xor(rs[i], 8, 64);
  }
  if (lr == 0) {
#pragma unroll
    for (int i = 0; i < 4; i++) rsum[wv][lq * 4 + i] = rs[i];
  }
  __syncthreads();
  if (tid < 16) {
    float s = 0.f;
#pragma unroll
    for (int w = 0; w < 8; w++) s += rsum[w][tid];
    rinv[n0 + tid] = 1.0f / s;
  }
}

// ---------------- Kernel 2: xpt[b*128+f][m] = bf16(x[b][m][f]), cols m>=NSEN -> 0
__global__ __launch_bounds__(256) void k_xpt(const float* __restrict__ x,
                                             unsigned short* __restrict__ xpt) {
  __shared__ unsigned short tile[64][72];
  const int t = threadIdx.x;
  const int m0 = blockIdx.x * 64;
  const int f0 = blockIdx.y * 64;
  const int b  = blockIdx.z;
  const int f4 = t & 15, mrow = t >> 4;
#pragma unroll
  for (int rep = 0; rep < 4; rep++) {
    int ml = mrow + rep * 16;
    int m = m0 + ml;
    float4 v = make_float4(0.f, 0.f, 0.f, 0.f);
    if (m < NSEN) v = *(const float4*)&x[((size_t)b * NSEN + m) * DIN + f0 + f4 * 4];
    tile[f4*4+0][ml] = f2bf(v.x);
    tile[f4*4+1][ml] = f2bf(v.y);
    tile[f4*4+2][ml] = f2bf(v.z);
    tile[f4*4+3][ml] = f2bf(v.w);
  }
  __syncthreads();
  const int seg = t & 7, fl0 = t >> 3;
#pragma unroll
  for (int it = 0; it < 2; it++) {
    int fl = fl0 + it * 32;
    int j = b * DIN + f0 + fl;
    uint4 v = *(const uint4*)&tile[fl][seg * 8];
    *(uint4*)&xpt[(size_t)j * NP + m0 + seg * 8] = v;
  }
}

// ---------------- Kernel 3: fused  out = relu(((P @ x) * rinv) @ W + bias) ------
// BM=64, BN=128, BK=64. 512 threads = 8 waves (2Mx4N), wave tile 32x32.
// 48 KB LDS 2-buffer -> 2 blocks/CU co-resident => 4 waves/SIMD (vs R5's 2).
// grid (64, 8): id%8 = m-tile%8 -> batch-cohort of each A panel on one XCD.
// Depth-1 prefetch, uniform 3 loads/thread, counted vmcnt(3), split lgkmcnt,
// setprio, XOR-swizzled LDS via pre-swizzled source.
__global__ __launch_bounds__(512, 4) void k_gemm1(const unsigned short* __restrict__ A,
                                                  const unsigned short* __restrict__ Bt,
                                                  const unsigned short* __restrict__ Wt,
                                                  const float* __restrict__ rinv,
                                                  const float* __restrict__ bias,
                                                  float* __restrict__ out) {
  __shared__ __align__(16) unsigned short smem[24576];  // 48 KB: A 2x4096 | B 2x8192
  const int tid = threadIdx.x;
  const int lane = tid & 63, wv = tid >> 6;
  const int wr = wv >> 2, wc = wv & 3;     // 2 x 4 wave grid, wave tile 32x32
  const int lr = lane & 15, lq = lane >> 4;
  const int m0 = blockIdx.x * 64;
  const int b  = blockIdx.y;
  const int c0 = b * 128;
  unsigned short* tA0 = smem;           // 2 * 4096 shorts
  unsigned short* tB0 = smem + 8192;    // 2 * 8192 shorts

  f32x4 acc[2][2];
#pragma unroll
  for (int p = 0; p < 2; p++)
#pragma unroll
    for (int q = 0; q < 2; q++) acc[p][q] = (f32x4){0.f, 0.f, 0.f, 0.f};

  // uniform 3 gl_lds16 per thread per STAGE (1 A + 2 B); source k-chunk pre-swizzled
#define STAGE(bufi, kb)                                                              \
  {                                                                                  \
    {                                                                                \
      int idx = tid;                                                                 \
      int row = idx >> 3;                                                            \
      int kc = ((idx & 7) ^ (row & 7)) << 3;                                         \
      gl_lds16(&A[(size_t)(m0 + row) * NP + (kb) + kc], &tA0[(bufi)*4096 + idx*8]);  \
    }                                                                                \
    _Pragma("unroll")                                                                \
    for (int s = 0; s < 2; s++) {                                                    \
      int idx = s * 512 + tid;                                                       \
      int row = idx >> 3;                                                            \
      int kc = ((idx & 7) ^ (row & 7)) << 3;                                         \
      gl_lds16(&Bt[(size_t)(c0 + row) * NP + (kb) + kc], &tB0[(bufi)*8192 + idx*8]); \
    }                                                                                \
  }

  STAGE(0, 0);

  for (int it = 0; it < 64; ++it) {
    const int cur = it & 1;
    if (it < 63) {
      STAGE(cur ^ 1, (it + 1) * 64);
      asm volatile("s_waitcnt vmcnt(3)" ::: "memory");  // cur's 3 landed; next 3 in flight
    } else {
      asm volatile("s_waitcnt vmcnt(0)" ::: "memory");
    }
    __builtin_amdgcn_s_barrier();

    bf16x8 af0[2], bf0[2], af1[2], bf1[2];
    {
      const int koff0 = (lq * 8) ^ ((lr & 7) << 3);
#pragma unroll
      for (int p = 0; p < 2; p++)
        af0[p] = *(const bf16x8*)&tA0[cur * 4096 + (wr * 32 + p * 16 + lr) * 64 + koff0];
#pragma unroll
      for (int q = 0; q < 2; q++)
        bf0[q] = *(const bf16x8*)&tB0[cur * 8192 + (wc * 32 + q * 16 + lr) * 64 + koff0];
    }
    __builtin_amdgcn_sched_barrier(0);  // keep sk0 reads first in issue order
    {
      const int koff1 = (32 + lq * 8) ^ ((lr & 7) << 3);
#pragma unroll
      for (int p = 0; p < 2; p++)
        af1[p] = *(const bf16x8*)&tA0[cur * 4096 + (wr * 32 + p * 16 + lr) * 64 + koff1];
#pragma unroll
      for (int q = 0; q < 2; q++)
        bf1[q] = *(const bf16x8*)&tB0[cur * 8192 + (wc * 32 + q * 16 + lr) * 64 + koff1];
    }
    asm volatile("s_waitcnt lgkmcnt(4)" ::: "memory");  // sk0's 4 reads done
    __builtin_amdgcn_sched_barrier(0);
    __builtin_amdgcn_s_setprio(1);
#pragma unroll
    for (int p = 0; p < 2; p++)
#pragma unroll
      for (int q = 0; q < 2; q++)
        acc[p][q] = __builtin_amdgcn_mfma_f32_16x16x32_bf16(af0[p], bf0[q], acc[p][q], 0, 0, 0);
    asm volatile("s_waitcnt lgkmcnt(0)" ::: "memory");
    __builtin_amdgcn_sched_barrier(0);
#pragma unroll
    for (int p = 0; p < 2; p++)
#pragma unroll
      for (int q = 0; q < 2; q++)
        acc[p][q] = __builtin_amdgcn_mfma_f32_16x16x32_bf16(af1[p], bf1[q], acc[p][q], 0, 0, 0);
    __builtin_amdgcn_s_setprio(0);
    __builtin_amdgcn_s_barrier();
  }
#undef STAGE

  // ---- fused epilogue: agg = acc * rinv[row]  ->  out = relu(agg @ W + bias) ----
  bf16x8 wf[2][4];  // [q][ks]
#pragma unroll
  for (int q = 0; q < 2; q++)
#pragma unroll
    for (int ks = 0; ks < 4; ks++)
      wf[q][ks] = *(const bf16x8*)&Wt[(size_t)(wc * 32 + q * 16 + lr) * DIN + ks * 32 + lq * 8];

  // eps aliases dead staging LDS: 64x136 bf16 = 17.4 KB
  unsigned short* eps = smem;
#pragma unroll
  for (int p = 0; p < 2; p++) {
    float rv[4];
#pragma unroll
    for (int i = 0; i < 4; i++)
      rv[i] = rinv[m0 + wr * 32 + p * 16 + lq * 4 + i];
#pragma unroll
    for (int q = 0; q < 2; q++)
#pragma unroll
      for (int i = 0; i < 4; i++)
        eps[(wr * 32 + p * 16 + lq * 4 + i) * 136 + wc * 32 + q * 16 + lr] =
            f2bf(acc[p][q][i] * rv[i]);
  }
  __syncthreads();

  f32x4 acc2[2][2];
#pragma unroll
  for (int p = 0; p < 2; p++)
#pragma unroll
    for (int q = 0; q < 2; q++) acc2[p][q] = (f32x4){0.f, 0.f, 0.f, 0.f};

#pragma unroll
  for (int ks = 0; ks < 4; ks++) {
    bf16x8 a2[2];
#pragma unroll
    for (int p = 0; p < 2; p++)
      a2[p] = *(const bf16x8*)&eps[(wr * 32 + p * 16 + lr) * 136 + ks * 32 + lq * 8];
#pragma unroll
    for (int p = 0; p < 2; p++)
#pragma unroll
      for (int q = 0; q < 2; q++)
        acc2[p][q] = __builtin_amdgcn_mfma_f32_16x16x32_bf16(a2[p], wf[q][ks], acc2[p][q], 0, 0, 0);
  }

#pragma unroll
  for (int p = 0; p < 2; p++)
#pragma unroll
    for (int q = 0; q < 2; q++) {
      const int o = wc * 32 + q * 16 + lr;
      const float bb = bias[o];
#pragma unroll
      for (int i = 0; i < 4; i++) {
        const int n = m0 + wr * 32 + p * 16 + lq * 4 + i;
        if (n < NSEN)
          out[((size_t)b * NSEN + n) * DOUT + o] = fmaxf(acc2[p][q][i] + bb, 0.f);
      }
    }
}

// ---------------- launch ---------------------------------------------------------
extern "C" void kernel_launch(void* const* d_in, const int* in_sizes, int n_in,
                              void* d_out, int out_size, void* d_ws, size_t ws_size,
                              hipStream_t stream) {
  const float* x    = (const float*)d_in[0];
  const float* E1   = (const float*)d_in[1];
  const float* E2   = (const float*)d_in[2];
  const float* W    = (const float*)d_in[3];
  const float* bias = (const float*)d_in[4];
  float* out = (float*)d_out;

  char* ws = (char*)d_ws;
  // layout: adjp 33554432 | xpt 8388608 | Wt 32768 | rinv 16384  (~42 MiB)
  unsigned short* adjp = (unsigned short*)(ws);
  unsigned short* xpt  = (unsigned short*)(ws + 33554432);
  unsigned short* wt   = (unsigned short*)(ws + 33554432 + 8388608);
  float*          rinv = (float*)(ws + 33554432 + 8388608 + 32768);

  k_adj<<<dim3(NSEN / 16 + 1), dim3(512), 0, stream>>>(E1, E2, W, adjp, rinv, wt);
  k_xpt<<<dim3(NP / 64, DIN / 64, BATCH), dim3(256), 0, stream>>>(x, xpt);
  k_gemm1<<<dim3(NP / 64, BATCH), dim3(512), 0, stream>>>(adjp, xpt, wt, rinv, bias, out);
}

// Round 8
// 72.175 us; speedup vs baseline: 1.3183x; 1.1168x over previous
//
#include <hip/hip_runtime.h>
#include <hip/hip_bf16.h>

#define NSEN 4000
#define NP   4096
#define DIN  128
#define DOUT 128
#define EDIM 16
#define BATCH 8

typedef __attribute__((ext_vector_type(8))) short bf16x8;
typedef __attribute__((ext_vector_type(4))) float f32x4;

__device__ __forceinline__ unsigned short f2bf(float f) {
  unsigned int u = __float_as_uint(f);
  unsigned int r = (u + 0x7FFFu + ((u >> 16) & 1u)) >> 16;
  return (unsigned short)r;
}
__device__ __forceinline__ float bf2f(unsigned short s) {
  unsigned int u = ((unsigned int)s) << 16;
  return __uint_as_float(u);
}

__device__ __forceinline__ void gl_lds16(const void* g, void* l) {
  __builtin_amdgcn_global_load_lds((const __attribute__((address_space(1))) void*)g,
                                   (__attribute__((address_space(3))) void*)l, 16, 0, 0);
}

// ---------------- Kernel 1 (merged prep): blocks 0..249: P=exp(relu(E1@E2^T)) + rinv;
// block 250: W transpose; blocks 251..762: x transpose/cast (two 256-thr sub-tiles).
__global__ __launch_bounds__(512) void k_prep(const float* __restrict__ E1,
                                              const float* __restrict__ E2,
                                              const float* __restrict__ W,
                                              const float* __restrict__ x,
                                              unsigned short* __restrict__ adjp,
                                              float* __restrict__ rinv,
                                              unsigned short* __restrict__ Wt,
                                              unsigned short* __restrict__ xpt) {
  __shared__ float rsum[8][16];
  __shared__ unsigned short xtile[2][64][72];
  const int bx = blockIdx.x;
  const int tid = threadIdx.x;

  if (bx == 250) {
    for (int i = tid; i < DIN * DOUT; i += 512) {
      int o = i >> 7, f = i & 127;
      Wt[i] = f2bf(W[(size_t)f * DOUT + o]);
    }
    return;
  }
  if (bx > 250) {
    // x-transpose: tile = (bx-251)*2 + (tid>>8); 1024 tiles of 64m x 64f
    const int tile = (bx - 251) * 2 + (tid >> 8);
    const int t = tid & 255;
    const int sub = tid >> 8;
    const int m0 = (tile & 63) * 64;
    const int f0 = ((tile >> 6) & 1) * 64;
    const int b  = tile >> 7;
    const int f4 = t & 15, mrow = t >> 4;
#pragma unroll
    for (int rep = 0; rep < 4; rep++) {
      int ml = mrow + rep * 16;
      int m = m0 + ml;
      float4 v = make_float4(0.f, 0.f, 0.f, 0.f);
      if (m < NSEN) v = *(const float4*)&x[((size_t)b * NSEN + m) * DIN + f0 + f4 * 4];
      xtile[sub][f4*4+0][ml] = f2bf(v.x);
      xtile[sub][f4*4+1][ml] = f2bf(v.y);
      xtile[sub][f4*4+2][ml] = f2bf(v.z);
      xtile[sub][f4*4+3][ml] = f2bf(v.w);
    }
    __syncthreads();
    const int seg = t & 7, fl0 = t >> 3;
#pragma unroll
    for (int it = 0; it < 2; it++) {
      int fl = fl0 + it * 32;
      int j = b * DIN + f0 + fl;
      uint4 v = *(const uint4*)&xtile[sub][fl][seg * 8];
      *(uint4*)&xpt[(size_t)j * NP + m0 + seg * 8] = v;
    }
    return;
  }

  // ---- adjacency rows n0..n0+15 (MFMA hi/lo split) ----
  const int lane = tid & 63, wv = tid >> 6;
  const int lr = lane & 15, lq = lane >> 4;
  const int n0 = bx * 16;

  float a[8];
  {
    const float* e1p = &E1[(size_t)(n0 + lr) * EDIM + (lq & 1) * 8];
    *(float4*)&a[0] = *(const float4*)e1p;
    *(float4*)&a[4] = *(const float4*)(e1p + 4);
  }
  bf16x8 af1, af2;
#pragma unroll
  for (int j = 0; j < 8; j++) {
    unsigned short hs = f2bf(a[j]);
    af1[j] = (short)hs;
    float lo = a[j] - bf2f(hs);
    af2[j] = (lq < 2) ? (short)f2bf(lo) : (short)0;
  }

  float rs[4] = {0.f, 0.f, 0.f, 0.f};
  for (int t = wv; t < NSEN / 16; t += 8) {
    const int m = t * 16 + lr;
    float bv[8];
    const float* e2p = &E2[(size_t)m * EDIM + (lq & 1) * 8];
    *(float4*)&bv[0] = *(const float4*)e2p;
    *(float4*)&bv[4] = *(const float4*)(e2p + 4);
    bf16x8 bfrag;
#pragma unroll
    for (int j = 0; j < 8; j++) {
      unsigned short hs = f2bf(bv[j]);
      if (lq < 2) bfrag[j] = (short)hs;
      else        bfrag[j] = (short)f2bf(bv[j] - bf2f(hs));
    }
    f32x4 c = (f32x4){0.f, 0.f, 0.f, 0.f};
    c = __builtin_amdgcn_mfma_f32_16x16x32_bf16(af1, bfrag, c, 0, 0, 0);
    c = __builtin_amdgcn_mfma_f32_16x16x32_bf16(af2, bfrag, c, 0, 0, 0);
#pragma unroll
    for (int i = 0; i < 4; i++) {
      float p = __expf(fmaxf(c[i], 0.f));
      rs[i] += p;
      adjp[(size_t)(n0 + lq * 4 + i) * NP + t * 16 + lr] = f2bf(p);
    }
  }
  for (int i = tid; i < 16 * (NP - NSEN); i += 512) {
    int r = i / (NP - NSEN), c = i % (NP - NSEN);
    adjp[(size_t)(n0 + r) * NP + NSEN + c] = 0;
  }
#pragma unroll
  for (int i = 0; i < 4; i++) {
    rs[i] += __shfl_xor(rs[i], 1, 64);
    rs[i] += __shfl_xor(rs[i], 2, 64);
    rs[i] += __shfl_xor(rs[i], 4, 64);
    rs[i] += __shfl_xor(rs[i], 8, 64);
  }
  if (lr == 0) {
#pragma unroll
    for (int i = 0; i < 4; i++) rsum[wv][lq * 4 + i] = rs[i];
  }
  __syncthreads();
  if (tid < 16) {
    float s = 0.f;
#pragma unroll
    for (int w = 0; w < 8; w++) s += rsum[w][tid];
    rinv[n0 + tid] = 1.0f / s;
  }
}

// ---------------- Kernel 2: split-K partial GEMM  part[kh] = A[:,kh] @ Bt^T ------
// BM=128, BN=128, BK=64, split-K=2. 4 waves (2x2), WAVE TILE 64x64 (r=0.5:
// 16 ds_read_b128 per 32 MFMAs). grid (64,8): x=2m+kh -> batch cohort of each
// A panel shares one XCD (bijective, 64%8==0). 64 KB LDS 2-buffer -> 2 blocks/CU
// => 2 waves/SIMD. Depth-1 prefetch, counted vmcnt(8), split lgkmcnt, setprio.
__global__ __launch_bounds__(256, 2) void k_gemm1(const unsigned short* __restrict__ A,
                                                  const unsigned short* __restrict__ Bt,
                                                  unsigned short* __restrict__ part) {
  __shared__ __align__(16) unsigned short smem[32768];  // 64 KB: A 2x8192 | B 2x8192
  const int tid = threadIdx.x;
  const int lane = tid & 63, wv = tid >> 6;
  const int wr = wv >> 1, wc = wv & 1;     // 2 x 2 wave grid, wave tile 64x64
  const int lr = lane & 15, lq = lane >> 4;
  const int gx = blockIdx.x;               // 0..63 = 2*mtile + kh
  const int m0 = (gx >> 1) * 128;
  const int kb0 = (gx & 1) * 2048;
  const int b  = blockIdx.y;
  const int c0 = b * 128;
  unsigned short* tA0 = smem;            // 2 * 8192 shorts
  unsigned short* tB0 = smem + 16384;    // 2 * 8192 shorts

  f32x4 acc[4][4];
#pragma unroll
  for (int p = 0; p < 4; p++)
#pragma unroll
    for (int q = 0; q < 4; q++) acc[p][q] = (f32x4){0.f, 0.f, 0.f, 0.f};

  // 8 gl_lds16 per thread per STAGE (4 A + 4 B); source k-chunk pre-swizzled
#define STAGE(bufi, kb)                                                              \
  {                                                                                  \
    _Pragma("unroll")                                                                \
    for (int s = 0; s < 4; s++) {                                                    \
      int idx = s * 256 + tid;                                                       \
      int row = idx >> 3;                                                            \
      int kc = ((idx & 7) ^ (row & 7)) << 3;                                         \
      gl_lds16(&A[(size_t)(m0 + row) * NP + (kb) + kc], &tA0[(bufi)*8192 + idx*8]);  \
      gl_lds16(&Bt[(size_t)(c0 + row) * NP + (kb) + kc], &tB0[(bufi)*8192 + idx*8]); \
    }                                                                                \
  }

  STAGE(0, kb0);

  for (int it = 0; it < 32; ++it) {
    const int cur = it & 1;
    if (it < 31) {
      STAGE(cur ^ 1, kb0 + (it + 1) * 64);
      asm volatile("s_waitcnt vmcnt(8)" ::: "memory");  // cur's 8 landed; next 8 in flight
    } else {
      asm volatile("s_waitcnt vmcnt(0)" ::: "memory");
    }
    __builtin_amdgcn_s_barrier();

    bf16x8 af0[4], bf0[4], af1[4], bf1[4];
    {
      const int koff0 = (lq * 8) ^ ((lr & 7) << 3);
#pragma unroll
      for (int p = 0; p < 4; p++)
        af0[p] = *(const bf16x8*)&tA0[cur * 8192 + (wr * 64 + p * 16 + lr) * 64 + koff0];
#pragma unroll
      for (int q = 0; q < 4; q++)
        bf0[q] = *(const bf16x8*)&tB0[cur * 8192 + (wc * 64 + q * 16 + lr) * 64 + koff0];
    }
    __builtin_amdgcn_sched_barrier(0);  // keep sk0 reads first in issue order
    {
      const int koff1 = (32 + lq * 8) ^ ((lr & 7) << 3);
#pragma unroll
      for (int p = 0; p < 4; p++)
        af1[p] = *(const bf16x8*)&tA0[cur * 8192 + (wr * 64 + p * 16 + lr) * 64 + koff1];
#pragma unroll
      for (int q = 0; q < 4; q++)
        bf1[q] = *(const bf16x8*)&tB0[cur * 8192 + (wc * 64 + q * 16 + lr) * 64 + koff1];
    }
    asm volatile("s_waitcnt lgkmcnt(8)" ::: "memory");  // sk0's 8 reads done
    __builtin_amdgcn_sched_barrier(0);
    __builtin_amdgcn_s_setprio(1);
#pragma unroll
    for (int p = 0; p < 4; p++)
#pragma unroll
      for (int q = 0; q < 4; q++)
        acc[p][q] = __builtin_amdgcn_mfma_f32_16x16x32_bf16(af0[p], bf0[q], acc[p][q], 0, 0, 0);
    asm volatile("s_waitcnt lgkmcnt(0)" ::: "memory");
    __builtin_amdgcn_sched_barrier(0);
#pragma unroll
    for (int p = 0; p < 4; p++)
#pragma unroll
      for (int q = 0; q < 4; q++)
        acc[p][q] = __builtin_amdgcn_mfma_f32_16x16x32_bf16(af1[p], bf1[q], acc[p][q], 0, 0, 0);
    __builtin_amdgcn_s_setprio(0);
    __builtin_amdgcn_s_barrier();
  }
#undef STAGE

  // epilogue: bf16 partial store part[kh][b][m][f]
  const int kh = gx & 1;
  unsigned short* pdst = part + ((size_t)(kh * BATCH + b) * NP + m0) * DIN;
#pragma unroll
  for (int p = 0; p < 4; p++)
#pragma unroll
    for (int q = 0; q < 4; q++) {
      const int col = wc * 64 + q * 16 + lr;
#pragma unroll
      for (int i = 0; i < 4; i++) {
        const int row = wr * 64 + p * 16 + lq * 4 + i;
        pdst[row * DIN + col] = f2bf(acc[p][q][i]);
      }
    }
}

// ---------------- Kernel 3: out = relu(((p0+p1) * rinv) @ W + bias) --------------
__global__ __launch_bounds__(256, 2) void k_fin(const unsigned short* __restrict__ part,
                                                const unsigned short* __restrict__ Wt,
                                                const float* __restrict__ rinv,
                                                const float* __restrict__ bias,
                                                float* __restrict__ out) {
  __shared__ __align__(16) unsigned short eps[64 * 136];
  const int tid = threadIdx.x;
  const int lane = tid & 63, wv = tid >> 6;
  const int wr = wv >> 1, wc = wv & 1;
  const int lr = lane & 15, lq = lane >> 4;
  const int m0 = blockIdx.x * 64;
  const int b = blockIdx.y;
  const size_t base = ((size_t)b * NP + m0) * DIN;
  const size_t khoff = (size_t)BATCH * NP * DIN;

  bf16x8 wf[4][4];  // [q][ks]
#pragma unroll
  for (int q = 0; q < 4; q++)
#pragma unroll
    for (int ks = 0; ks < 4; ks++)
      wf[q][ks] = *(const bf16x8*)&Wt[(size_t)(wc * 64 + q * 16 + lr) * DIN + ks * 32 + lq * 8];

  // combine partials: 64 rows x 16 8-col chunks = 1024 chunks, 4 per thread
#pragma unroll
  for (int s = 0; s < 4; s++) {
    int c = s * 256 + tid;
    int row = c >> 4, col = (c & 15) * 8;
    bf16x8 p0 = *(const bf16x8*)&part[base + row * DIN + col];
    bf16x8 p1 = *(const bf16x8*)&part[khoff + base + row * DIN + col];
    float rv = rinv[m0 + row];
    unsigned short tmp[8];
#pragma unroll
    for (int j = 0; j < 8; j++)
      tmp[j] = f2bf((bf2f((unsigned short)p0[j]) + bf2f((unsigned short)p1[j])) * rv);
    *(bf16x8*)&eps[row * 136 + col] = *(bf16x8*)tmp;
  }
  __syncthreads();

  f32x4 acc2[2][4];
#pragma unroll
  for (int p = 0; p < 2; p++)
#pragma unroll
    for (int q = 0; q < 4; q++) acc2[p][q] = (f32x4){0.f, 0.f, 0.f, 0.f};

#pragma unroll
  for (int ks = 0; ks < 4; ks++) {
    bf16x8 a2[2];
#pragma unroll
    for (int p = 0; p < 2; p++)
      a2[p] = *(const bf16x8*)&eps[(wr * 32 + p * 16 + lr) * 136 + ks * 32 + lq * 8];
#pragma unroll
    for (int p = 0; p < 2; p++)
#pragma unroll
      for (int q = 0; q < 4; q++)
        acc2[p][q] = __builtin_amdgcn_mfma_f32_16x16x32_bf16(a2[p], wf[q][ks], acc2[p][q], 0, 0, 0);
  }

#pragma unroll
  for (int p = 0; p < 2; p++)
#pragma unroll
    for (int q = 0; q < 4; q++) {
      const int o = wc * 64 + q * 16 + lr;
      const float bb = bias[o];
#pragma unroll
      for (int i = 0; i < 4; i++) {
        const int n = m0 + wr * 32 + p * 16 + lq * 4 + i;
        if (n < NSEN)
          out[((size_t)b * NSEN + n) * DOUT + o] = fmaxf(acc2[p][q][i] + bb, 0.f);
      }
    }
}

// ---------------- launch ---------------------------------------------------------
extern "C" void kernel_launch(void* const* d_in, const int* in_sizes, int n_in,
                              void* d_out, int out_size, void* d_ws, size_t ws_size,
                              hipStream_t stream) {
  const float* x    = (const float*)d_in[0];
  const float* E1   = (const float*)d_in[1];
  const float* E2   = (const float*)d_in[2];
  const float* W    = (const float*)d_in[3];
  const float* bias = (const float*)d_in[4];
  float* out = (float*)d_out;

  char* ws = (char*)d_ws;
  // layout: adjp 33554432 | xpt 8388608 | Wt 32768 | rinv 16384 | part 16777216 (~56 MiB)
  unsigned short* adjp = (unsigned short*)(ws);
  unsigned short* xpt  = (unsigned short*)(ws + 33554432);
  unsigned short* wt   = (unsigned short*)(ws + 33554432 + 8388608);
  float*          rinv = (float*)(ws + 33554432 + 8388608 + 32768);
  unsigned short* part = (unsigned short*)(ws + 33554432 + 8388608 + 32768 + 16384);

  k_prep<<<dim3(763), dim3(512), 0, stream>>>(E1, E2, W, x, adjp, rinv, wt, xpt);
  k_gemm1<<<dim3(64, BATCH), dim3(256), 0, stream>>>(adjp, xpt, part);
  k_fin<<<dim3(63, BATCH), dim3(256), 0, stream>>>(part, wt, rinv, bias, out);
}